// Round 2
// baseline (603.945 us; speedup 1.0000x reference)
//
#include <hip/hip_runtime.h>
#include <stdint.h>

#define NB     4
#define SEQ    2048
#define NH     16
#define DHD    64
#define DM     1024
#define MTOT   (NB*SEQ)     // 8192

typedef __attribute__((ext_vector_type(8))) short bf16x8;
typedef __attribute__((ext_vector_type(4))) float f32x4;

__device__ __forceinline__ short f2bf(float f) {
  uint32_t u = __float_as_uint(f);
  u = (u + 0x7FFFu + ((u >> 16) & 1u)) >> 16;   // RNE, finite inputs only
  return (short)u;
}

__device__ __forceinline__ uint32_t cvtpk(float lo, float hi) {
  uint32_t r;
  asm("v_cvt_pk_bf16_f32 %0, %1, %2" : "=v"(r) : "v"(lo), "v"(hi));
  return r;
}

__device__ __forceinline__ f32x4 mfma16(bf16x8 a, bf16x8 b, f32x4 c) {
  return __builtin_amdgcn_mfma_f32_16x16x32_bf16(a, b, c, 0, 0, 0);
}

__device__ __forceinline__ void async16(const void* g, void* l) {
  __builtin_amdgcn_global_load_lds(
      (const __attribute__((address_space(1))) void*)g,
      (__attribute__((address_space(3))) void*)l, 16, 0, 0);
}

// ---- cast x f32 -> bf16 ----
__global__ void k_cast(const float* __restrict__ in, short* __restrict__ out, int n) {
  int i = (blockIdx.x * blockDim.x + threadIdx.x) * 8;
  if (i >= n) return;
  float4 a = *reinterpret_cast<const float4*>(in + i);
  float4 b = *reinterpret_cast<const float4*>(in + i + 4);
  uint32_t w0 = cvtpk(a.x, a.y), w1 = cvtpk(a.z, a.w);
  uint32_t w2 = cvtpk(b.x, b.y), w3 = cvtpk(b.z, b.w);
  uint4 v = {w0, w1, w2, w3};
  *reinterpret_cast<uint4*>(out + i) = v;
}

// ---- mask -> additive float bias ----
__global__ void k_maskbias(const int* __restrict__ pm, float* __restrict__ fb, int n) {
  int i = blockIdx.x * blockDim.x + threadIdx.x;
  if (i < n) fb[i] = pm[i] ? 0.0f : -1e30f;
}

// ---- transpose+cast W [K=1024][N=1024] f32 -> Wt [N][K] bf16 ----
__global__ void k_transpose(const float* __restrict__ in, short* __restrict__ out) {
  __shared__ float tile[32][33];
  int n0 = blockIdx.x * 32, k0 = blockIdx.y * 32;
  int tx = threadIdx.x, ty = threadIdx.y;   // block (32,8)
  #pragma unroll
  for (int i = 0; i < 32; i += 8)
    tile[ty + i][tx] = in[(size_t)(k0 + ty + i) * DM + n0 + tx];
  __syncthreads();
  #pragma unroll
  for (int i = 0; i < 32; i += 8)
    out[(size_t)(n0 + ty + i) * DM + k0 + tx] = f2bf(tile[tx][ty + i]);
}

// ---- 128x128x(K=1024) bf16 MFMA GEMM, B given transposed [N][K] ----
// MODE 0: C bf16 [M][DM]   (Q,K)  -- epilogue scaled by `scale`
// MODE 1: C bf16 written as Vt[b][n][s] = [ (b*DM+n)*SEQ + s ]   (V)
// MODE 2: C f32 [M][DM]    (final output)
template<int MODE>
__global__ void __launch_bounds__(256) k_gemm(const short* __restrict__ A,
                                              const short* __restrict__ Bt,
                                              const float* __restrict__ bias,
                                              void* __restrict__ Cv, float scale) {
  __shared__ short lA[128 * 32];
  __shared__ short lB[128 * 32];
  int m0 = blockIdx.x * 128, n0 = blockIdx.y * 128;
  int tid = threadIdx.x, lane = tid & 63, w = tid >> 6;
  int wr = w >> 1, wc = w & 1;
  int l15 = lane & 15, lg = lane >> 4;
  f32x4 acc[4][4] = {};

  int r0 = tid >> 2, c0 = (tid & 3) * 8;                 // chunk 0..255
  int r1 = (tid + 256) >> 2, c1 = ((tid + 256) & 3) * 8; // chunk 256..511
  const short* ga0 = A + (size_t)(m0 + r0) * DM + c0;
  const short* ga1 = A + (size_t)(m0 + r1) * DM + c1;
  const short* gb0 = Bt + (size_t)(n0 + r0) * DM + c0;
  const short* gb1 = Bt + (size_t)(n0 + r1) * DM + c1;
  short* lA0 = lA + w * 512;           // wave-uniform LDS bases (+lane*16B by HW)
  short* lA1 = lA + 2048 + w * 512;
  short* lB0 = lB + w * 512;
  short* lB1 = lB + 2048 + w * 512;

  for (int k0 = 0; k0 < DM; k0 += 32) {
    async16(ga0 + k0, lA0);
    async16(ga1 + k0, lA1);
    async16(gb0 + k0, lB0);
    async16(gb1 + k0, lB1);
    __syncthreads();
    bf16x8 af[4], bfr[4];
    #pragma unroll
    for (int i = 0; i < 4; ++i) {
      af[i]  = *reinterpret_cast<const bf16x8*>(lA + (wr * 64 + i * 16 + l15) * 32 + lg * 8);
      bfr[i] = *reinterpret_cast<const bf16x8*>(lB + (wc * 64 + i * 16 + l15) * 32 + lg * 8);
    }
    #pragma unroll
    for (int i = 0; i < 4; ++i)
      #pragma unroll
      for (int j = 0; j < 4; ++j)
        acc[i][j] = mfma16(af[i], bfr[j], acc[i][j]);
    __syncthreads();
  }

  #pragma unroll
  for (int j = 0; j < 4; ++j) {
    int cg = n0 + wc * 64 + j * 16 + l15;
    float bv = bias[cg];
    #pragma unroll
    for (int i = 0; i < 4; ++i) {
      #pragma unroll
      for (int r = 0; r < 4; ++r) {
        int rg = m0 + wr * 64 + i * 16 + lg * 4 + r;
        float val = (acc[i][j][r] + bv) * scale;
        if (MODE == 0)
          ((short*)Cv)[(size_t)rg * DM + cg] = f2bf(val);
        else if (MODE == 1)
          ((short*)Cv)[((size_t)((rg >> 11) * DM + cg)) * SEQ + (rg & 2047)] = f2bf(val);
        else
          ((float*)Cv)[(size_t)rg * DM + cg] = val;
      }
    }
  }
}

// ---- flash attention, swapped-operand (S^T = K·Q^T), ALiBi + padding mask ----
// grid (SEQ/64, NB*NH), block 256 = 4 independent waves; each wave: 16 q rows.
// Per KV tile of 64: S^T via mfma(K,Q) -> lane l15 = q, regs = 16 kv values.
// Softmax fully in-register (+2 shfl_xor). P^T redistribution via tiny
// wave-private LDS strip (4x ds_write_b64 + 2x ds_read_b128). No barriers.
__global__ void __launch_bounds__(256) k_attn(const short* __restrict__ Q,
                                              const short* __restrict__ Kb,
                                              const short* __restrict__ Vt,
                                              const float* __restrict__ fbias,
                                              short* __restrict__ O) {
  __shared__ uint32_t pbuf[4 * 16 * 36];   // [wave][l15][t(4)][lg(4)][d(2)], stride 36 dwords
  int qt = blockIdx.x, bh = blockIdx.y;
  int b = bh >> 4, h = bh & 15;
  int tid = threadIdx.x, lane = tid & 63, w = tid >> 6;
  int l15 = lane & 15, lg = lane >> 4;
  int q0 = qt * 64 + w * 16;
  float c2 = exp2f(-0.5f * (float)(h + 1)) * 0.125f;   // slope/sqrt(64)

  // Q as B-fragments (lane l15 = q col, elems = dh). Q is pre-scaled by 1/8.
  const short* qp = Q + (size_t)(b * SEQ + q0 + l15) * DM + h * DHD + lg * 8;
  bf16x8 bq0 = *reinterpret_cast<const bf16x8*>(qp);
  bf16x8 bq1 = *reinterpret_cast<const bf16x8*>(qp + 32);

  const short* kbase = Kb + (size_t)(b * SEQ) * DM + h * DHD + lg * 8;
  const short* vbase = Vt + (size_t)bh * DHD * SEQ + (size_t)l15 * SEQ + lg * 8;
  const float* fb = fbias + b * SEQ;
  uint32_t* wb = pbuf + w * 576 + l15 * 36;

  float mrun = -1e30f, ssum = 0.0f;
  f32x4 acc[4] = {};                     // O^T: dh = td*16+lg*4+r, q = l15
  float d0 = (float)(q0 + l15) - (float)(lg * 4);   // qi - (kv base); -= 64 per iter

  for (int kt = 0; kt < SEQ; kt += 64) {
    // K A-fragments (lane l15 = kv row, elems = dh)
    const short* kp = kbase + (size_t)kt * DM;
    bf16x8 ka[4][2];
    #pragma unroll
    for (int t = 0; t < 4; ++t) {
      ka[t][0] = *reinterpret_cast<const bf16x8*>(kp + (size_t)(t * 16 + l15) * DM);
      ka[t][1] = *reinterpret_cast<const bf16x8*>(kp + (size_t)(t * 16 + l15) * DM + 32);
    }
    f32x4 st[4];
    #pragma unroll
    for (int t = 0; t < 4; ++t) {
      f32x4 z = {};
      z = mfma16(ka[t][0], bq0, z);
      st[t] = mfma16(ka[t][1], bq1, z);
    }

    // V^T A-fragments issued early (latency hides under softmax)
    bf16x8 va[4][2];
    #pragma unroll
    for (int td = 0; td < 4; ++td) {
      va[td][0] = *reinterpret_cast<const bf16x8*>(vbase + (size_t)(td * 16) * SEQ + kt);
      va[td][1] = *reinterpret_cast<const bf16x8*>(vbase + (size_t)(td * 16) * SEQ + kt + 32);
    }

    float4 fb4[4];
    #pragma unroll
    for (int t = 0; t < 4; ++t)
      fb4[t] = *reinterpret_cast<const float4*>(fb + kt + t * 16 + lg * 4);

    // logits: l = S + fbias - c2*|qi - j|
    float l[4][4];
    #pragma unroll
    for (int t = 0; t < 4; ++t) {
      float f0 = fb4[t].x, f1 = fb4[t].y, f2v = fb4[t].z, f3 = fb4[t].w;
      l[t][0] = fmaf(-c2, fabsf(d0 - (float)(t * 16 + 0)), st[t][0] + f0);
      l[t][1] = fmaf(-c2, fabsf(d0 - (float)(t * 16 + 1)), st[t][1] + f1);
      l[t][2] = fmaf(-c2, fabsf(d0 - (float)(t * 16 + 2)), st[t][2] + f2v);
      l[t][3] = fmaf(-c2, fabsf(d0 - (float)(t * 16 + 3)), st[t][3] + f3);
    }

    // row max: in-register tree + xor16 + xor32
    float tmax = l[0][0];
    #pragma unroll
    for (int t = 0; t < 4; ++t)
      #pragma unroll
      for (int r = 0; r < 4; ++r)
        tmax = fmaxf(tmax, l[t][r]);
    tmax = fmaxf(tmax, __shfl_xor(tmax, 16));
    tmax = fmaxf(tmax, __shfl_xor(tmax, 32));

    float mn = fmaxf(mrun, tmax);
    float fsc = __expf(mrun - mn);
    mrun = mn;

    float rs = 0.0f;
    #pragma unroll
    for (int t = 0; t < 4; ++t)
      #pragma unroll
      for (int r = 0; r < 4; ++r) {
        float p = __expf(l[t][r] - mn);
        l[t][r] = p;
        rs += p;
      }
    rs += __shfl_xor(rs, 16);
    rs += __shfl_xor(rs, 32);
    ssum = ssum * fsc + rs;
    #pragma unroll
    for (int td = 0; td < 4; ++td) acc[td] *= fsc;

    // P^T -> bf16 pairs -> wave-private LDS strip
    #pragma unroll
    for (int t = 0; t < 4; ++t) {
      uint2 wv = { cvtpk(l[t][0], l[t][1]), cvtpk(l[t][2], l[t][3]) };
      *reinterpret_cast<uint2*>(wb + t * 8 + lg * 2) = wv;
    }
    asm volatile("s_waitcnt lgkmcnt(0)" ::: "memory");
    __builtin_amdgcn_sched_barrier(0);

    // PV: O^T += V^T · P^T  (two 32-k steps)
    #pragma unroll
    for (int ks = 0; ks < 2; ++ks) {
      int t = ks * 2 + (lg >> 1);
      bf16x8 pf = *reinterpret_cast<const bf16x8*>(wb + t * 8 + (lg & 1) * 4);
      #pragma unroll
      for (int td = 0; td < 4; ++td)
        acc[td] = mfma16(va[td][ks], pf, acc[td]);
    }
    d0 -= 64.0f;
  }

  float inv = 1.0f / ssum;
  short* op = O + (size_t)(b * SEQ + q0 + l15) * DM + h * DHD;
  #pragma unroll
  for (int td = 0; td < 4; ++td) {
    uint2 wv = { cvtpk(acc[td][0] * inv, acc[td][1] * inv),
                 cvtpk(acc[td][2] * inv, acc[td][3] * inv) };
    *reinterpret_cast<uint2*>(op + td * 16 + lg * 4) = wv;
  }
}

extern "C" void kernel_launch(void* const* d_in, const int* in_sizes, int n_in,
                              void* d_out, int out_size, void* d_ws, size_t ws_size,
                              hipStream_t stream) {
  const float* x  = (const float*)d_in[0];
  const float* Wq = (const float*)d_in[1];
  const float* bq = (const float*)d_in[2];
  const float* Wk = (const float*)d_in[3];
  const float* bk = (const float*)d_in[4];
  const float* Wv = (const float*)d_in[5];
  const float* bv = (const float*)d_in[6];
  const float* Wo = (const float*)d_in[7];
  const float* bo = (const float*)d_in[8];
  const int*   pm = (const int*)d_in[9];

  char* ws = (char*)d_ws;
  const size_t MB = 1ull << 20;
  short* xb  = (short*)(ws + 0 * MB);    // 16 MB: x bf16
  short* q   = (short*)(ws + 16 * MB);   // 16 MB
  short* k   = (short*)(ws + 32 * MB);   // 16 MB
  short* vt  = (short*)(ws + 48 * MB);   // 16 MB, [b,h,dh,s]
  short* ob  = (short*)(ws + 64 * MB);   // 16 MB: attention out bf16
  short* wqt = (short*)(ws + 80 * MB);   // 2 MB each
  short* wkt = (short*)(ws + 82 * MB);
  short* wvt = (short*)(ws + 84 * MB);
  short* wot = (short*)(ws + 86 * MB);
  float* fbias = (float*)(ws + 88 * MB); // 32 KB

  k_cast<<<dim3(MTOT * DM / 8 / 256), dim3(256), 0, stream>>>(x, xb, MTOT * DM);
  k_maskbias<<<dim3(MTOT / 256), dim3(256), 0, stream>>>(pm, fbias, MTOT);
  k_transpose<<<dim3(32, 32), dim3(32, 8), 0, stream>>>(Wq, wqt);
  k_transpose<<<dim3(32, 32), dim3(32, 8), 0, stream>>>(Wk, wkt);
  k_transpose<<<dim3(32, 32), dim3(32, 8), 0, stream>>>(Wv, wvt);
  k_transpose<<<dim3(32, 32), dim3(32, 8), 0, stream>>>(Wo, wot);
  k_gemm<0><<<dim3(64, 8), dim3(256), 0, stream>>>(xb, wqt, bq, q, 0.125f);
  k_gemm<0><<<dim3(64, 8), dim3(256), 0, stream>>>(xb, wkt, bk, k, 1.0f);
  k_gemm<1><<<dim3(64, 8), dim3(256), 0, stream>>>(xb, wvt, bv, vt, 1.0f);
  k_attn<<<dim3(SEQ / 64, NB * NH), dim3(256), 0, stream>>>(q, k, vt, fbias, ob);
  k_gemm<2><<<dim3(64, 8), dim3(256), 0, stream>>>(ob, wot, bo, d_out, 1.0f);
}

// Round 3
// 272.792 us; speedup vs baseline: 2.2139x; 2.2139x over previous
//
#include <hip/hip_runtime.h>
#include <stdint.h>

#define NB     4
#define SEQ    2048
#define NH     16
#define DHD    64
#define DM     1024
#define MTOT   (NB*SEQ)     // 8192

typedef __attribute__((ext_vector_type(8))) short bf16x8;
typedef __attribute__((ext_vector_type(4))) float f32x4;

__device__ __forceinline__ short f2bf(float f) {
  uint32_t u = __float_as_uint(f);
  u = (u + 0x7FFFu + ((u >> 16) & 1u)) >> 16;   // RNE, finite inputs only
  return (short)u;
}

__device__ __forceinline__ uint32_t cvtpk(float lo, float hi) {
  uint32_t r;
  asm("v_cvt_pk_bf16_f32 %0, %1, %2" : "=v"(r) : "v"(lo), "v"(hi));
  return r;
}

__device__ __forceinline__ f32x4 mfma16(bf16x8 a, bf16x8 b, f32x4 c) {
  return __builtin_amdgcn_mfma_f32_16x16x32_bf16(a, b, c, 0, 0, 0);
}

__device__ __forceinline__ void async16(const void* g, void* l) {
  __builtin_amdgcn_global_load_lds(
      (const __attribute__((address_space(1))) void*)g,
      (__attribute__((address_space(3))) void*)l, 16, 0, 0);
}

// ---- cast x f32 -> bf16 (scalar casts: compiler emits cvt_pk itself, m240) ----
__global__ void k_cast(const float* __restrict__ in, short* __restrict__ out, int n) {
  int i = (blockIdx.x * blockDim.x + threadIdx.x) * 8;
  if (i >= n) return;
  float4 a = *reinterpret_cast<const float4*>(in + i);
  float4 b = *reinterpret_cast<const float4*>(in + i + 4);
  bf16x8 v;
  v[0] = f2bf(a.x); v[1] = f2bf(a.y); v[2] = f2bf(a.z); v[3] = f2bf(a.w);
  v[4] = f2bf(b.x); v[5] = f2bf(b.y); v[6] = f2bf(b.z); v[7] = f2bf(b.w);
  *reinterpret_cast<bf16x8*>(out + i) = v;
}

// ---- mask -> additive float bias ----
__global__ void k_maskbias(const int* __restrict__ pm, float* __restrict__ fb, int n) {
  int i = blockIdx.x * blockDim.x + threadIdx.x;
  if (i < n) fb[i] = pm[i] ? 0.0f : -1e30f;
}

// ---- transpose+cast W [K=1024][N=1024] f32 -> Wt [N][K] bf16 ----
__global__ void k_transpose(const float* __restrict__ in, short* __restrict__ out) {
  __shared__ float tile[32][33];
  int n0 = blockIdx.x * 32, k0 = blockIdx.y * 32;
  int tx = threadIdx.x, ty = threadIdx.y;   // block (32,8)
  #pragma unroll
  for (int i = 0; i < 32; i += 8)
    tile[ty + i][tx] = in[(size_t)(k0 + ty + i) * DM + n0 + tx];
  __syncthreads();
  #pragma unroll
  for (int i = 0; i < 32; i += 8)
    out[(size_t)(n0 + ty + i) * DM + k0 + tx] = f2bf(tile[tx][ty + i]);
}

// ---- 128x128x(K=1024) bf16 MFMA GEMM, B given transposed [N][K] ----
// MODE 0: C bf16 [M][DM]   (Q,K)  -- epilogue scaled by `scale`
// MODE 1: C bf16 written as Vt[b][n][s] = [ (b*DM+n)*SEQ + s ]   (V)
// MODE 2: C f32 [M][DM]    (final output)
template<int MODE>
__global__ void __launch_bounds__(256) k_gemm(const short* __restrict__ A,
                                              const short* __restrict__ Bt,
                                              const float* __restrict__ bias,
                                              void* __restrict__ Cv, float scale) {
  __shared__ short lA[128 * 32];
  __shared__ short lB[128 * 32];
  int m0 = blockIdx.x * 128, n0 = blockIdx.y * 128;
  int tid = threadIdx.x, lane = tid & 63, w = tid >> 6;
  int wr = w >> 1, wc = w & 1;
  int l15 = lane & 15, lg = lane >> 4;
  f32x4 acc[4][4] = {};

  int r0 = tid >> 2, c0 = (tid & 3) * 8;                 // chunk 0..255
  int r1 = (tid + 256) >> 2, c1 = ((tid + 256) & 3) * 8; // chunk 256..511
  const short* ga0 = A + (size_t)(m0 + r0) * DM + c0;
  const short* ga1 = A + (size_t)(m0 + r1) * DM + c1;
  const short* gb0 = Bt + (size_t)(n0 + r0) * DM + c0;
  const short* gb1 = Bt + (size_t)(n0 + r1) * DM + c1;
  short* lA0 = lA + w * 512;           // wave-uniform LDS bases (+lane*16B by HW)
  short* lA1 = lA + 2048 + w * 512;
  short* lB0 = lB + w * 512;
  short* lB1 = lB + 2048 + w * 512;

  for (int k0 = 0; k0 < DM; k0 += 32) {
    async16(ga0 + k0, lA0);
    async16(ga1 + k0, lA1);
    async16(gb0 + k0, lB0);
    async16(gb1 + k0, lB1);
    __syncthreads();
    bf16x8 af[4], bfr[4];
    #pragma unroll
    for (int i = 0; i < 4; ++i) {
      af[i]  = *reinterpret_cast<const bf16x8*>(lA + (wr * 64 + i * 16 + l15) * 32 + lg * 8);
      bfr[i] = *reinterpret_cast<const bf16x8*>(lB + (wc * 64 + i * 16 + l15) * 32 + lg * 8);
    }
    #pragma unroll
    for (int i = 0; i < 4; ++i)
      #pragma unroll
      for (int j = 0; j < 4; ++j)
        acc[i][j] = mfma16(af[i], bfr[j], acc[i][j]);
    __syncthreads();
  }

  #pragma unroll
  for (int j = 0; j < 4; ++j) {
    int cg = n0 + wc * 64 + j * 16 + l15;
    float bv = bias[cg];
    #pragma unroll
    for (int i = 0; i < 4; ++i) {
      #pragma unroll
      for (int r = 0; r < 4; ++r) {
        int rg = m0 + wr * 64 + i * 16 + lg * 4 + r;
        float val = (acc[i][j][r] + bv) * scale;
        if (MODE == 0)
          ((short*)Cv)[(size_t)rg * DM + cg] = f2bf(val);
        else if (MODE == 1)
          ((short*)Cv)[((size_t)((rg >> 11) * DM + cg)) * SEQ + (rg & 2047)] = f2bf(val);
        else
          ((float*)Cv)[(size_t)rg * DM + cg] = val;
      }
    }
  }
}

// ---- flash attention, swapped-operand (S^T = K·Q^T), ALiBi + padding mask ----
// grid (SEQ/64, NB*NH), block 256 = 4 waves sharing one (b,h).
// K/V tiles (64 rows x 64) staged to LDS ONCE per block via global_load_lds,
// XOR-swizzled on the global source (linear LDS dest, m173); fragment
// ds_read_b128 applies the same XOR -> ~2-way banked instead of 32-way.
// Softmax in-register; P^T via wave-private LDS strip; 2 barriers/tile.
__global__ void __launch_bounds__(256) k_attn(const short* __restrict__ Q,
                                              const short* __restrict__ Kb,
                                              const short* __restrict__ Vt,
                                              const float* __restrict__ fbias,
                                              short* __restrict__ O) {
  __shared__ short lK[64 * 64];            // 8 KB, row-major [kv][dh], swizzled
  __shared__ short lV[64 * 64];            // 8 KB, [dh][s-tile], swizzled
  __shared__ uint32_t pbuf[4 * 16 * 36];   // wave-private P strips
  int qt = blockIdx.x, bh = blockIdx.y;
  int b = bh >> 4, h = bh & 15;
  int tid = threadIdx.x, lane = tid & 63, w = tid >> 6;
  int l15 = lane & 15, lg = lane >> 4;
  int q0 = qt * 64 + w * 16;
  float c2 = exp2f(-0.5f * (float)(h + 1)) * 0.125f;   // slope/sqrt(64)

  // Q as B-fragments (lane l15 = q col, elems = dh). Q pre-scaled by 1/8.
  const short* qp = Q + (size_t)(b * SEQ + q0 + l15) * DM + h * DHD + lg * 8;
  bf16x8 bq0 = *reinterpret_cast<const bf16x8*>(qp);
  bf16x8 bq1 = *reinterpret_cast<const bf16x8*>(qp + 32);

  // staging: thread -> (row, chunk); global src pre-swizzled, LDS dest linear
  int srow0 = w * 8 + (lane >> 3);         // issue0 rows 0..31
  int srow1 = srow0 + 32;                  // issue1 rows 32..63
  int sc0 = (lane & 7) ^ (srow0 & 7);
  int sc1 = (lane & 7) ^ (srow1 & 7);
  const short* kg0 = Kb + (size_t)(b * SEQ + srow0) * DM + h * DHD + sc0 * 8;
  const short* kg1 = Kb + (size_t)(b * SEQ + srow1) * DM + h * DHD + sc1 * 8;
  const short* vg0 = Vt + ((size_t)bh * DHD + srow0) * SEQ + sc0 * 8;
  const short* vg1 = Vt + ((size_t)bh * DHD + srow1) * SEQ + sc1 * 8;
  short* dK0 = lK + w * 512;
  short* dK1 = lK + 2048 + w * 512;
  short* dV0 = lV + w * 512;
  short* dV1 = lV + 2048 + w * 512;

  const float* fb = fbias + b * SEQ;
  uint32_t* wb = pbuf + w * 576 + l15 * 36;

  float mrun = -1e30f, ssum = 0.0f;
  f32x4 acc[4] = {};                       // O^T: dh = td*16+lg*4+r, q = l15
  float d0 = (float)(q0 + l15) - (float)(lg * 4);

  for (int kt = 0; kt < SEQ; kt += 64) {
    async16(kg0, dK0);
    async16(kg1, dK1);
    async16(vg0, dV0);
    async16(vg1, dV1);
    kg0 += (size_t)64 * DM; kg1 += (size_t)64 * DM; vg0 += 64; vg1 += 64;

    float4 fb4[4];
    #pragma unroll
    for (int t = 0; t < 4; ++t)
      fb4[t] = *reinterpret_cast<const float4*>(fb + kt + t * 16 + lg * 4);

    __syncthreads();                       // staged K/V visible

    // QK^T: S^T[kv][q] from LDS K fragments
    f32x4 st[4];
    #pragma unroll
    for (int t = 0; t < 4; ++t) {
      int row = t * 16 + l15, sw = row & 7;
      bf16x8 k0 = *reinterpret_cast<const bf16x8*>(lK + row * 64 + (lg ^ sw) * 8);
      bf16x8 k1 = *reinterpret_cast<const bf16x8*>(lK + row * 64 + ((lg + 4) ^ sw) * 8);
      f32x4 z = {};
      z = mfma16(k0, bq0, z);
      st[t] = mfma16(k1, bq1, z);
    }

    // logits: l = S + fbias - c2*|qi - j|
    float l[4][4];
    #pragma unroll
    for (int t = 0; t < 4; ++t) {
      l[t][0] = fmaf(-c2, fabsf(d0 - (float)(t * 16 + 0)), st[t][0] + fb4[t].x);
      l[t][1] = fmaf(-c2, fabsf(d0 - (float)(t * 16 + 1)), st[t][1] + fb4[t].y);
      l[t][2] = fmaf(-c2, fabsf(d0 - (float)(t * 16 + 2)), st[t][2] + fb4[t].z);
      l[t][3] = fmaf(-c2, fabsf(d0 - (float)(t * 16 + 3)), st[t][3] + fb4[t].w);
    }

    // row max: in-register tree + xor16 + xor32
    float tmax = l[0][0];
    #pragma unroll
    for (int t = 0; t < 4; ++t)
      #pragma unroll
      for (int r = 0; r < 4; ++r)
        tmax = fmaxf(tmax, l[t][r]);
    tmax = fmaxf(tmax, __shfl_xor(tmax, 16));
    tmax = fmaxf(tmax, __shfl_xor(tmax, 32));

    float mn = fmaxf(mrun, tmax);
    float fsc = __expf(mrun - mn);
    mrun = mn;

    float rs = 0.0f;
    #pragma unroll
    for (int t = 0; t < 4; ++t)
      #pragma unroll
      for (int r = 0; r < 4; ++r) {
        float p = __expf(l[t][r] - mn);
        l[t][r] = p;
        rs += p;
      }
    rs += __shfl_xor(rs, 16);
    rs += __shfl_xor(rs, 32);
    ssum = ssum * fsc + rs;
    #pragma unroll
    for (int td = 0; td < 4; ++td) acc[td] *= fsc;

    // P^T -> bf16 pairs -> wave-private LDS strip
    #pragma unroll
    for (int t = 0; t < 4; ++t) {
      uint2 wv = { cvtpk(l[t][0], l[t][1]), cvtpk(l[t][2], l[t][3]) };
      *reinterpret_cast<uint2*>(wb + t * 8 + lg * 2) = wv;
    }
    asm volatile("s_waitcnt lgkmcnt(0)" ::: "memory");
    __builtin_amdgcn_sched_barrier(0);

    // PV: O^T += V^T · P^T  (two 32-k steps), V from LDS
    #pragma unroll
    for (int ks = 0; ks < 2; ++ks) {
      int t = ks * 2 + (lg >> 1);
      bf16x8 pf = *reinterpret_cast<const bf16x8*>(wb + t * 8 + (lg & 1) * 4);
      #pragma unroll
      for (int td = 0; td < 4; ++td) {
        int row = td * 16 + l15, sw = row & 7;
        bf16x8 vf = *reinterpret_cast<const bf16x8*>(lV + row * 64 + ((ks * 4 + lg) ^ sw) * 8);
        acc[td] = mfma16(vf, pf, acc[td]);
      }
    }
    d0 -= 64.0f;
    __syncthreads();                       // all waves done with lK/lV
  }

  float inv = 1.0f / ssum;
  short* op = O + (size_t)(b * SEQ + q0 + l15) * DM + h * DHD;
  #pragma unroll
  for (int td = 0; td < 4; ++td) {
    uint2 wv = { cvtpk(acc[td][0] * inv, acc[td][1] * inv),
                 cvtpk(acc[td][2] * inv, acc[td][3] * inv) };
    *reinterpret_cast<uint2*>(op + td * 16 + lg * 4) = wv;
  }
}

extern "C" void kernel_launch(void* const* d_in, const int* in_sizes, int n_in,
                              void* d_out, int out_size, void* d_ws, size_t ws_size,
                              hipStream_t stream) {
  const float* x  = (const float*)d_in[0];
  const float* Wq = (const float*)d_in[1];
  const float* bq = (const float*)d_in[2];
  const float* Wk = (const float*)d_in[3];
  const float* bk = (const float*)d_in[4];
  const float* Wv = (const float*)d_in[5];
  const float* bv = (const float*)d_in[6];
  const float* Wo = (const float*)d_in[7];
  const float* bo = (const float*)d_in[8];
  const int*   pm = (const int*)d_in[9];

  char* ws = (char*)d_ws;
  const size_t MB = 1ull << 20;
  short* xb  = (short*)(ws + 0 * MB);    // 16 MB: x bf16
  short* q   = (short*)(ws + 16 * MB);   // 16 MB
  short* k   = (short*)(ws + 32 * MB);   // 16 MB
  short* vt  = (short*)(ws + 48 * MB);   // 16 MB, [b,h,dh,s]
  short* ob  = (short*)(ws + 64 * MB);   // 16 MB: attention out bf16
  short* wqt = (short*)(ws + 80 * MB);   // 2 MB each
  short* wkt = (short*)(ws + 82 * MB);
  short* wvt = (short*)(ws + 84 * MB);
  short* wot = (short*)(ws + 86 * MB);
  float* fbias = (float*)(ws + 88 * MB); // 32 KB

  k_cast<<<dim3(MTOT * DM / 8 / 256), dim3(256), 0, stream>>>(x, xb, MTOT * DM);
  k_maskbias<<<dim3(MTOT / 256), dim3(256), 0, stream>>>(pm, fbias, MTOT);
  k_transpose<<<dim3(32, 32), dim3(32, 8), 0, stream>>>(Wq, wqt);
  k_transpose<<<dim3(32, 32), dim3(32, 8), 0, stream>>>(Wk, wkt);
  k_transpose<<<dim3(32, 32), dim3(32, 8), 0, stream>>>(Wv, wvt);
  k_transpose<<<dim3(32, 32), dim3(32, 8), 0, stream>>>(Wo, wot);
  k_gemm<0><<<dim3(64, 8), dim3(256), 0, stream>>>(xb, wqt, bq, q, 0.125f);
  k_gemm<0><<<dim3(64, 8), dim3(256), 0, stream>>>(xb, wkt, bk, k, 1.0f);
  k_gemm<1><<<dim3(64, 8), dim3(256), 0, stream>>>(xb, wvt, bv, vt, 1.0f);
  k_attn<<<dim3(SEQ / 64, NB * NH), dim3(256), 0, stream>>>(q, k, vt, fbias, ob);
  k_gemm<2><<<dim3(64, 8), dim3(256), 0, stream>>>(ob, wot, bo, d_out, 1.0f);
}